// Round 10
// baseline (2035.966 us; speedup 1.0000x reference)
//
#include <hip/hip_runtime.h>

// LSTM: VOCAB=100, INPUT=512, HIDDEN=1024, BATCH=64, SEQ=512
// out = latent[64][512][1024] f32, then h_f[64][1024], c_f[64][1024]
// v10: 2-group pipelined halves. 256 blocks = 2 pairs x 128 js (8 units each).
//      Each block alternates batch-groups A/B (16 batches each, same weights) so
//      the inter-block h handoff of one group hides under the other's compute.
//      hstage in MFMA-fragment order (write-once slots, flag-gated, cached reads),
//      full-M16 MFMA with 4-way K-split + LDS reduce, latent via plain L2 stores.

typedef _Float16 f16x8 __attribute__((ext_vector_type(8)));
typedef float    f32x4 __attribute__((ext_vector_type(4)));
typedef unsigned int u32x4 __attribute__((ext_vector_type(4)));

#define VOCABN 100

// ---------------- K0: zx_table[v][g*1024+n] = emb[v] . Wg[n,0:512] + b_g[n] ----------------
__global__ void k0_zxtable(const float* __restrict__ emb,
                           const float* __restrict__ Wf, const float* __restrict__ bf,
                           const float* __restrict__ Wi, const float* __restrict__ bi,
                           const float* __restrict__ Wo, const float* __restrict__ bo,
                           const float* __restrict__ Wg, const float* __restrict__ bg_,
                           float* __restrict__ zx) {
  const int bid = blockIdx.x;            // 256 blocks: (gate, 16-unit chunk)
  const int g = bid >> 6, chunk = bid & 63;
  const float* W = (g==0)?Wf:(g==1)?Wi:(g==2)?Wo:Wg;
  const float* B = (g==0)?bf:(g==1)?bi:(g==2)?bo:bg_;
  __shared__ float Wl[16][516];
  const int tid = threadIdx.x;
  for (int i = tid; i < 2048; i += 256) {
    int r = i >> 7, c4 = i & 127;
    float4 v = *(const float4*)&W[(size_t)(chunk*16 + r)*1536 + c4*4];
    Wl[r][c4*4+0]=v.x; Wl[r][c4*4+1]=v.y; Wl[r][c4*4+2]=v.z; Wl[r][c4*4+3]=v.w;
  }
  __syncthreads();
  const int u = tid & 15, vi = tid >> 4;
  for (int v0 = 0; v0 < VOCABN; v0 += 16) {
    int v = v0 + vi;
    if (v < VOCABN) {
      const float* er = emb + (size_t)v*512;
      float acc = 0.f;
      #pragma unroll 8
      for (int k = 0; k < 512; k++) acc += er[k]*Wl[u][k];
      zx[(size_t)v*4096 + g*1024 + chunk*16 + u] = acc + B[chunk*16 + u];
    }
  }
}

// ---------------- K1: Whh fp16 conversion + h0 -> init slot (fragment layout) ----------------
__global__ void k1_prep(const float* __restrict__ Wf, const float* __restrict__ Wi,
                        const float* __restrict__ Wo, const float* __restrict__ Wg,
                        const float* __restrict__ h0,
                        _Float16* __restrict__ Whh, char* __restrict__ h0slot) {
  const int bid = blockIdx.x, tid = threadIdx.x;
  if (bid < 1024) {
    #pragma unroll
    for (int i = 0; i < 4; i++) {
      int F = bid*1024 + i*256 + tid;            // float4 index, 2^20 total
      int g = F >> 18;
      int rem = F & ((1<<18)-1);
      int n = rem >> 8, k4 = rem & 255;
      const float* W = (g==0)?Wf:(g==1)?Wi:(g==2)?Wo:Wg;
      float4 v = *(const float4*)&W[(size_t)n*1536 + 512 + k4*4];
      _Float16 h4[4] = {(_Float16)v.x,(_Float16)v.y,(_Float16)v.z,(_Float16)v.w};
      *(unsigned long long*)&Whh[((size_t)g<<20) + (n<<10) + (k4<<2)] =
          *(unsigned long long*)h4;
    }
  } else {
    int j = bid - 1024;                          // brow 0..63
    int gi = j >> 4, row = j & 15;
    int u0 = tid*4;
    float4 v = *(const float4*)&h0[(size_t)j*1024 + u0];
    _Float16 h4[4] = {(_Float16)v.x,(_Float16)v.y,(_Float16)v.z,(_Float16)v.w};
    char* dst = h0slot + ((size_t)gi << 15) + (u0>>3)*256 + row*16 + (u0&7)*2;
    *(unsigned long long*)dst = *(unsigned long long*)h4;
  }
}

// ---------------- Main: 256 blocks = 2 pairs x 128 js, 512 thr, 2 halves/step ----------------
template<bool BIG>
__global__ __launch_bounds__(512, 1) void lstm_main(
    const int* __restrict__ X, const float* __restrict__ c0,
    const float* __restrict__ zx, const _Float16* __restrict__ Whh,
    char* __restrict__ hstage, int* __restrict__ flags, float* __restrict__ out)
{
  extern __shared__ char smem[];               // stage[2]: 0/32768; zp f32 @65536 (17408B)
  const int bid = blockIdx.x;
  const int p   = bid >> 7;                    // pair 0/1
  const int js  = bid & 127;                   // 8 units = 32 gate-cols
  const int tid = threadIdx.x;
  const int w = tid >> 6, l = tid & 63;
  const int lm = l & 15, lh = l >> 4;
  const int ct = w & 1, kq = w >> 1;           // coltile, K-quarter
  float* zpf = (float*)(smem + 65536);

  // ---- weights: 8 x f16x8 (32 VGPR) pinned: col = ct*16+lm, K-slice kq*256 ----
  f16x8 bw[8];
  {
    const int cw = ct*16 + lm;
    const _Float16* wp = Whh + ((size_t)(cw & 3) << 20)
        + ((size_t)(js*8 + (cw >> 2)) << 10) + kq*256 + lh*8;
    #pragma unroll
    for (int j = 0; j < 8; j++)
      asm volatile("global_load_dwordx4 %0, %1, off" : "=&v"(bw[j]) : "v"(wp + j*32));
    asm volatile("s_waitcnt vmcnt(0)");
    __builtin_amdgcn_sched_barrier(0);
  }

  // ---- gate-lane role: (batch b, gate-col cf) ----
  const int b  = tid >> 5, cf = tid & 31;
  const int g  = cf & 3, uloc = cf >> 2;
  const int ucol = js*8 + uloc;
  const int gi0 = p*2, gi1 = p*2 + 1;
  const int brow0 = gi0*16 + b, brow1 = gi1*16 + b;
  float cA = c0[(size_t)brow0*1024 + ucol];
  float cB = c0[(size_t)brow1*1024 + ucol];
  const int* XrA = X + (size_t)brow0*512;
  const int* XrB = X + (size_t)brow1*512;
  int xvA = XrA[0], xvB = XrB[0];
  float* latA = out + (size_t)brow0*524288 + ucol;
  float* latB = out + (size_t)brow1*524288 + ucol;
  const int SINIT = BIG ? 511 : 7;

  // ---- prologue: LDS[0] <- h0(gi0) from init slot ----
  {
    const char* sb = hstage + (((size_t)SINIT*4 + gi0) << 15) + (size_t)tid*16;
    u32x4 q0, q1, q2, q3;
    asm volatile("global_load_dwordx4 %0, %4, off sc1\n\t"
                 "global_load_dwordx4 %1, %5, off sc1\n\t"
                 "global_load_dwordx4 %2, %6, off sc1\n\t"
                 "global_load_dwordx4 %3, %7, off sc1\n\t"
                 "s_waitcnt vmcnt(0)"
                 : "=&v"(q0), "=&v"(q1), "=&v"(q2), "=&v"(q3)
                 : "v"(sb), "v"(sb+8192), "v"(sb+16384), "v"(sb+24576));
    char* ld = smem + (size_t)tid*16;
    *(u32x4*)(ld) = q0; *(u32x4*)(ld + 8192) = q1;
    *(u32x4*)(ld + 16384) = q2; *(u32x4*)(ld + 24576) = q3;
    __syncthreads();
  }

#define HALF(PH, GI, CST, XV, XRP, LATP) {                                     \
  float zxv = zx[(size_t)(XV)*4096 + (g<<10) + ucol];                          \
  if (t < 511) (XV) = (XRP)[t+1];                                              \
  /* MFMA: [16b x 16c] partial over K=256 */                                   \
  const char* Ab = smem + ((PH)<<15) + l*16;                                   \
  f32x4 a0 = {0,0,0,0}, a1 = {0,0,0,0};                                        \
  _Pragma("unroll")                                                            \
  for (int j = 0; j < 8; j += 2) {                                             \
    f16x8 x0 = *(const f16x8*)(Ab + ((kq*8 + j)     << 10));                   \
    f16x8 x1 = *(const f16x8*)(Ab + ((kq*8 + j + 1) << 10));                   \
    a0 = __builtin_amdgcn_mfma_f32_16x16x32_f16(x0, bw[j],   a0, 0, 0, 0);     \
    a1 = __builtin_amdgcn_mfma_f32_16x16x32_f16(x1, bw[j+1], a1, 0, 0, 0);     \
  }                                                                            \
  f32x4 z4 = a0 + a1;                                                          \
  float* zw = zpf + (((PH)*2 + ct)*4 + kq)*272 + lh*68 + lm;                   \
  zw[0] = z4[0]; zw[17] = z4[1]; zw[34] = z4[2]; zw[51] = z4[3];               \
  asm volatile("s_waitcnt lgkmcnt(0)\n\ts_barrier" ::: "memory");   /* S2 */   \
  /* K-split reduce + gates (all 512 lanes) */                                 \
  const float* zr = zpf + ((PH)*2 + (cf>>4))*1088 + b*17 + (cf & 15);          \
  float zz = (zr[0] + zr[272]) + (zr[544] + zr[816]) + zxv;                    \
  float ex = __expf((g==3) ? -2.f*zz : -zz);                                   \
  float sgv = 1.f/(1.f + ex);                                                  \
  float gv = (g==3) ? (2.f*sgv - 1.f) : sgv;                                   \
  float r1 = __shfl_xor(gv, 1);                                                \
  float se = (g & 1) ? r1 : gv;                                                \
  float so = (g & 1) ? gv : r1;                                                \
  float r2e = __shfl_xor(se, 2);                                               \
  float r2o = __shfl_xor(so, 2);                                               \
  float ff = (g & 2) ? r2e : se;                                               \
  float ii = (g & 2) ? r2o : so;                                               \
  float oo = (g & 2) ? se : r2e;                                               \
  float gg = (g & 2) ? so : r2o;                                               \
  float cnew = ff*(CST) + ii*gg;                                               \
  (CST) = cnew;                                                                \
  float e2 = __expf(2.f*cnew);                                                 \
  float h = oo*(1.f - 2.f/(e2 + 1.f));                                         \
  /* stage next half's group: poll quad flag, then load */                     \
  u32x4 sv0, sv1, sv2, sv3;                                                    \
  const bool dostage = !((PH) == 1 && t == 511);                               \
  const int s = t - 1 + (PH);                                                  \
  const int gip = p*2 + ((PH)^1);                                              \
  if (dostage) {                                                               \
    if (s >= 0) {                                                              \
      const int* fp = flags + (((s<<2) + gip) << 7) + ((tid >> 4) << 2);       \
      u32x4 fv; int spin = 0;                                                  \
      do {                                                                     \
        asm volatile("global_load_dwordx4 %0, %1, off sc1\n\t"                 \
                     "s_waitcnt vmcnt(0)" : "=&v"(fv) : "v"(fp));              \
      } while ((fv[0] & fv[1] & fv[2] & fv[3]) == 0 && ++spin < (1<<16));      \
    }                                                                          \
    const int slot = (s < 0) ? SINIT : (BIG ? s : (s & 7));                    \
    const char* sb = hstage + (((size_t)slot*4 + gip) << 15) + (size_t)tid*16; \
    if (BIG && s >= 0) {          /* write-once slots -> plain cached loads */ \
      sv0 = *(const u32x4*)(sb);                                               \
      sv1 = *(const u32x4*)(sb + 8192);                                        \
      sv2 = *(const u32x4*)(sb + 16384);                                       \
      sv3 = *(const u32x4*)(sb + 24576);                                       \
    } else {                                                                   \
      asm volatile("global_load_dwordx4 %0, %4, off sc1\n\t"                   \
                   "global_load_dwordx4 %1, %5, off sc1\n\t"                   \
                   "global_load_dwordx4 %2, %6, off sc1\n\t"                   \
                   "global_load_dwordx4 %3, %7, off sc1\n\t"                   \
                   "s_waitcnt vmcnt(0)"                                        \
                   : "=&v"(sv0), "=&v"(sv1), "=&v"(sv2), "=&v"(sv3)            \
                   : "v"(sb), "v"(sb+8192), "v"(sb+16384), "v"(sb+24576));     \
    }                                                                          \
  }                                                                            \
  /* publish h(t): pack 8 units -> one 16B sc1 store per batch */              \
  unsigned hu = (unsigned)__builtin_bit_cast(unsigned short, (_Float16)h);     \
  unsigned q1p = (unsigned)__shfl_xor((int)hu, 4);                             \
  unsigned w01 = (cf & 4) ? ((q1p & 0xffffu) | (hu << 16))                     \
                          : ((hu & 0xffffu) | (q1p << 16));                    \
  unsigned q2p = (unsigned)__shfl_xor((int)w01, 8);                            \
  unsigned e0 = (cf & 8) ? q2p : w01;                                          \
  unsigned e1 = (cf & 8) ? w01 : q2p;                                          \
  unsigned q3a = (unsigned)__shfl_xor((int)e0, 16);                            \
  unsigned q3b = (unsigned)__shfl_xor((int)e1, 16);                            \
  if (t < 511 && cf == 0) {                                                    \
    u32x4 pk; pk[0]=e0; pk[1]=e1; pk[2]=q3a; pk[3]=q3b;                        \
    const int pslot = BIG ? t : (t & 7);                                       \
    char* pb = hstage + (((size_t)pslot*4 + (GI)) << 15) + js*256 + b*16;      \
    asm volatile("global_store_dwordx4 %0, %1, off sc1"                        \
                 :: "v"(pb), "v"(pk) : "memory");                              \
  }                                                                            \
  if (dostage) {                                                               \
    char* ld = smem + (((PH)^1) << 15) + (size_t)tid*16;                       \
    *(u32x4*)(ld) = sv0; *(u32x4*)(ld + 8192) = sv1;                           \
    *(u32x4*)(ld + 16384) = sv2; *(u32x4*)(ld + 24576) = sv3;                  \
  }                                                                            \
  asm volatile("s_waitcnt vmcnt(0) lgkmcnt(0)\n\ts_barrier" ::: "memory");     \
  if (t < 511 && tid == 0) {                                                   \
    int one = 1;                                                               \
    int* fb = flags + (((t<<2) + (GI)) << 7) + ((js & 31) << 2) + (js >> 5);   \
    asm volatile("global_store_dword %0, %1, off sc1"                          \
                 :: "v"(fb), "v"(one) : "memory");                             \
  }                                                                            \
  if (g == 0) {                                                                \
    (LATP)[(size_t)t*1024] = h;              /* plain store -> L2 writeback */ \
    if (t == 511) {                                                            \
      out[33554432 + ((size_t)((GI)*16 + b) << 10) + ucol] = h;                \
      out[33619968 + ((size_t)((GI)*16 + b) << 10) + ucol] = cnew;             \
    }                                                                          \
  }                                                                            \
}

  for (int t = 0; t < 512; t++) {
    HALF(0, gi0, cA, xvA, XrA, latA)
    HALF(1, gi1, cB, xvB, XrB, latB)
  }
#undef HALF
}

extern "C" void kernel_launch(void* const* d_in, const int* in_sizes, int n_in,
                              void* d_out, int out_size, void* d_ws, size_t ws_size,
                              hipStream_t stream) {
  const int*   X   = (const int*)  d_in[0];
  const float* h0  = (const float*)d_in[1];
  const float* c0  = (const float*)d_in[2];
  const float* emb = (const float*)d_in[3];
  const float* Wf  = (const float*)d_in[4];  const float* bf = (const float*)d_in[5];
  const float* Wi  = (const float*)d_in[6];  const float* bi = (const float*)d_in[7];
  const float* Wo  = (const float*)d_in[8];  const float* bo = (const float*)d_in[9];
  const float* Wg  = (const float*)d_in[10]; const float* bg = (const float*)d_in[11];
  float* out = (float*)d_out;

  char* ws = (char*)d_ws;
  float*    zx  = (float*)   ws;                 // 1,638,400 B
  _Float16* Whh = (_Float16*)(ws + 1638400);     // 8,388,608 B
  const size_t base = 1638400 + 8388608;

  const size_t need_big = base + (size_t)512*131072 + 1048576;   // 78,184,448
  const bool   big      = ws_size >= need_big;
  const size_t nslots   = big ? 512 : 8;
  char* hstage = ws + base;
  int*  flags  = (int*)(ws + base + nslots*131072);
  const int SINIT = big ? 511 : 7;
  char* h0slot = hstage + ((size_t)SINIT*4 << 15);

  hipMemsetAsync(flags, 0, 1048576, stream);
  k0_zxtable<<<256, 256, 0, stream>>>(emb, Wf, bf, Wi, bi, Wo, bo, Wg, bg, zx);
  k1_prep<<<1088, 256, 0, stream>>>(Wf, Wi, Wo, Wg, h0, Whh, h0slot);
  // LDS: 2x32KB stage + 17.4KB zp = 82,944 B -> 1 block/CU
  if (big)
    lstm_main<true><<<256, 512, 82944, stream>>>(X, c0, zx, Whh, hstage, flags, out);
  else
    lstm_main<false><<<256, 512, 82944, stream>>>(X, c0, zx, Whh, hstage, flags, out);
}